// Round 10
// baseline (232.823 us; speedup 1.0000x reference)
//
#include <hip/hip_runtime.h>
#include <hip/hip_bf16.h>
#include <math.h>

// Dims fixed by setup_inputs: B=4, S=512, T=256, H=1024, V=32000
// Pure single-fp16 operands. r8 measured absmax 0.0078 < 0.02 threshold.
// r10: gemm1 also zeroes d_out rows [0,925) via interleaved NT stores;
// softmax_scatter zeroes only rows >= 925 (which cover the d_out tail
// intermediates -- safe by stream order, gemm2 consumed them already).
typedef _Float16 f16x8 __attribute__((ext_vector_type(8)));
typedef float    f32x4 __attribute__((ext_vector_type(4)));

#define ZROW   925
#define ZTOTF4 7400000      // 925*128000/16 float4s zeroed by gemm1
#define ZPERBLK 14454       // ceil(ZTOTF4/512)

__device__ __forceinline__ unsigned short h2us(_Float16 v) {
    return *(unsigned short*)&v;
}

// async global->LDS, 16B per lane; LDS dest = wave-uniform base + lane*16
__device__ __forceinline__ void gl2lds16(const void* g, void* l) {
    __builtin_amdgcn_global_load_lds(
        (const __attribute__((address_space(1))) unsigned int*)(uintptr_t)g,
        (__attribute__((address_space(3))) unsigned int*)(unsigned int)(uintptr_t)l,
        16, 0, 0);
}

// ---- merged prep: fp32->fp16 (enc_in, dec_in) + W transpose->fp16 ----
__global__ __launch_bounds__(256) void prep(const float* __restrict__ encf,
                                            unsigned short* __restrict__ eh,
                                            const float* __restrict__ decf,
                                            unsigned short* __restrict__ dh,
                                            const float* __restrict__ W,
                                            unsigned short* __restrict__ Wth) {
    const int bid = blockIdx.x;
    if (bid < 3072) {
        const float* src; unsigned short* ph; int i;
        if (bid < 2048) { src = encf; ph = eh; i = bid * 256 + threadIdx.x; }
        else            { src = decf; ph = dh; i = (bid - 2048) * 256 + threadIdx.x; }
        const float4 v = ((const float4*)src)[i];
        ushort4 h;
        h.x = h2us((_Float16)v.x);
        h.y = h2us((_Float16)v.y);
        h.z = h2us((_Float16)v.z);
        h.w = h2us((_Float16)v.w);
        ((ushort4*)ph)[i] = h;
        return;
    }
    // transpose+convert W: Wt[n][k] = fp16(W[k][n])
    __shared__ float tile[64][65];
    const int tb = bid - 3072;
    const int k0 = (tb >> 4) * 64, n0 = (tb & 15) * 64;
    const int c = threadIdx.x & 63, r0 = threadIdx.x >> 6;
    #pragma unroll
    for (int p = 0; p < 16; ++p) {
        int r = r0 + p * 4;
        tile[r][c] = W[(size_t)(k0 + r) * 1024 + n0 + c];
    }
    __syncthreads();
    #pragma unroll
    for (int p = 0; p < 16; ++p) {
        int rn = r0 + p * 4;
        float v = tile[c][rn];               // = W[k0+c][n0+rn]
        Wth[(size_t)(n0 + rn) * 1024 + k0 + c] = h2us((_Float16)v);
    }
}

// ---- fp16 MFMA GEMM, 64x64 tile, BK=64, B^T [N][K], single-fp16 A and B.
// Staging via global_load_lds(16B), XOR-swizzled LDS k-chunks.
// EPI 0: fp32 partials (split-K). EPI 1: tanh(acc+bias[n]) -> fp16, plus
//        zero-duty: NT-store zeros into zdst (d_out rows [0,ZROW)).
template <int EPI>
__global__ __launch_bounds__(256) void gemm_f16(
    const unsigned short* __restrict__ Ah,
    const unsigned short* __restrict__ Bh,
    const float* __restrict__ bias,
    float* __restrict__ Cf, unsigned short* __restrict__ Ch,
    f32x4* __restrict__ zdst,
    int N, int K, int kIter, int ksplit,
    long long aBatch, long long bBatch, long long cBatch, long long cPart) {

    const int z = blockIdx.z;
    const int batch = z / ksplit;
    const int ks = z - batch * ksplit;
    Ah += (size_t)batch * aBatch;
    Bh += (size_t)batch * bBatch;
    const int kOff = ks * kIter * 64;

    __shared__ __align__(16) unsigned short sAh[64 * 64];
    __shared__ __align__(16) unsigned short sBh[64 * 64];

    const int t = threadIdx.x;
    const int lane = t & 63;
    const int w = t >> 6;
    const int wm = w >> 1, wn = w & 1;
    const int ln15 = lane & 15, q4 = lane >> 4;

    const int row0 = blockIdx.y * 64;
    const int col0 = blockIdx.x * 64;

    // zero-duty range (EPI==1 only): this block owns float4s [zBase, zEnd)
    int zBase = 0, zEnd = 0;
    if (EPI == 1) {
        const int lin = blockIdx.y * gridDim.x + blockIdx.x;
        zBase = lin * ZPERBLK;
        zEnd  = min(zBase + ZPERBLK, ZTOTF4);
    }
    const f32x4 zero4 = {0.f, 0.f, 0.f, 0.f};

    // staging: 512 16B-chunks per array; wave w pass p covers chunks w*128+p*64+lane.
    // LDS chunk (r, ch) holds global k-chunk (ch ^ (r&7))  [bank swizzle]
    const int c0 = w * 128 + lane;
    const int r0s = c0 >> 3, g0 = ((c0 & 7) ^ (r0s & 7)) * 8;
    const int c1 = c0 + 64;
    const int r1s = c1 >> 3, g1 = ((c1 & 7) ^ (r1s & 7)) * 8;
    const size_t a0 = (size_t)(row0 + r0s) * K + kOff + g0;
    const size_t a1 = (size_t)(row0 + r1s) * K + kOff + g1;
    const size_t b0 = (size_t)(col0 + r0s) * K + kOff + g0;
    const size_t b1 = (size_t)(col0 + r1s) * K + kOff + g1;

    f32x4 acc[2][2] = {};

    for (int kk = 0; kk < kIter; ++kk) {
        const int k0 = kk * 64;
        gl2lds16(Ah + a0 + k0, &sAh[c0 * 8]);
        gl2lds16(Ah + a1 + k0, &sAh[c1 * 8]);
        gl2lds16(Bh + b0 + k0, &sBh[c0 * 8]);
        gl2lds16(Bh + b1 + k0, &sBh[c1 * 8]);

        // trickle out zero-stores while staging loads are in flight
        if (EPI == 1) {
            const int base = zBase + kk * 1024 + t;
            #pragma unroll
            for (int u = 0; u < 4; ++u) {
                int idx = base + u * 256;
                if (idx < zEnd) __builtin_nontemporal_store(zero4, &zdst[idx]);
            }
        }
        __syncthreads();

        #pragma unroll
        for (int kh = 0; kh < 2; ++kh) {
            f16x8 ah[2], bh[2];
            #pragma unroll
            for (int i = 0; i < 2; ++i) {
                int rr = wm * 32 + i * 16 + ln15;
                int off = rr * 64 + (((kh * 4 + q4) ^ (rr & 7)) * 8);
                ah[i] = *(const f16x8*)&sAh[off];
            }
            #pragma unroll
            for (int j = 0; j < 2; ++j) {
                int rr = wn * 32 + j * 16 + ln15;
                int off = rr * 64 + (((kh * 4 + q4) ^ (rr & 7)) * 8);
                bh[j] = *(const f16x8*)&sBh[off];
            }
            #pragma unroll
            for (int i = 0; i < 2; ++i)
                #pragma unroll
                for (int j = 0; j < 2; ++j)
                    acc[i][j] = __builtin_amdgcn_mfma_f32_16x16x32_f16(ah[i], bh[j], acc[i][j], 0, 0, 0);
        }
        __syncthreads();
    }

    // epilogue: C layout col=lane&15, row=(lane>>4)*4+reg
    float* outp = (EPI == 0) ? (Cf + (size_t)batch * cBatch + (size_t)ks * cPart) : nullptr;
    #pragma unroll
    for (int i = 0; i < 2; ++i)
        #pragma unroll
        for (int j = 0; j < 2; ++j) {
            int colg = col0 + wn * 32 + j * 16 + ln15;
            float bv = (EPI == 1) ? bias[colg] : 0.0f;
            #pragma unroll
            for (int r = 0; r < 4; ++r) {
                int rowg = row0 + wm * 32 + i * 16 + q4 * 4 + r;
                if (EPI == 0) {
                    outp[(size_t)rowg * N + colg] = acc[i][j][r];
                } else {
                    _Float16 h = (_Float16)tanhf(acc[i][j][r] + bv);
                    Ch[(size_t)rowg * N + colg] = h2us(h);
                }
            }
        }
}

// ---- fused: sum 4 split-K parts + bias, softmax over S, scatter.
// Rows >= ZROW also zero their own vocab row (covers the d_out tail region).
__inline__ __device__ float waveReduceMax(float v) {
    #pragma unroll
    for (int off = 32; off > 0; off >>= 1) v = fmaxf(v, __shfl_down(v, off));
    return v;
}
__inline__ __device__ float waveReduceSum(float v) {
    #pragma unroll
    for (int off = 32; off > 0; off >>= 1) v += __shfl_down(v, off);
    return v;
}

__global__ __launch_bounds__(256) void softmax_scatter(const float* __restrict__ scores,
                                                       const int* __restrict__ tokens,
                                                       const float* __restrict__ ibias,
                                                       float* __restrict__ out) {
    const int row = blockIdx.x;          // b*T + t
    const int b = row >> 8;              // T = 256
    const size_t plane = (size_t)4 * 256 * 512;
    const float* s0 = scores + (size_t)row * 512;
    const float* bi = ibias + (size_t)b * 512;
    const int* tok = tokens + (size_t)b * 512;
    float* o = out + (size_t)row * 32000;

    __shared__ float red[4];
    const int tid = threadIdx.x;
    const int wid = tid >> 6, lane = tid & 63;

    float v0 = bi[tid], v1 = bi[tid + 256];
    #pragma unroll
    for (int p = 0; p < 4; ++p) {
        v0 += s0[p * plane + tid];
        v1 += s0[p * plane + tid + 256];
    }

    float m = fmaxf(v0, v1);
    m = waveReduceMax(m);
    if (lane == 0) red[wid] = m;
    __syncthreads();
    if (tid == 0) red[0] = fmaxf(fmaxf(red[0], red[1]), fmaxf(red[2], red[3]));
    __syncthreads();
    const float rowmax = red[0];
    __syncthreads();

    float e0 = __expf(v0 - rowmax);
    float e1 = __expf(v1 - rowmax);
    float s = e0 + e1;
    s = waveReduceSum(s);
    if (lane == 0) red[wid] = s;
    __syncthreads();
    if (tid == 0) red[0] = red[0] + red[1] + red[2] + red[3];
    __syncthreads();
    const float inv = 1.0f / red[0];

    // rows < ZROW were zeroed by gemm1 (two kernels ago); tail rows zero here
    if (row >= ZROW) {
        float4 z = make_float4(0.f, 0.f, 0.f, 0.f);
        float4* o4 = (float4*)o;
        for (int i = tid; i < 8000; i += 256) o4[i] = z;
    }
    __syncthreads();

    atomicAdd(&o[tok[tid]],       e0 * inv);
    atomicAdd(&o[tok[tid + 256]], e1 * inv);
}

extern "C" void kernel_launch(void* const* d_in, const int* in_sizes, int n_in,
                              void* d_out, int out_size, void* d_ws, size_t ws_size,
                              hipStream_t stream) {
    const int*   inputs  = (const int*)d_in[0];    // [B,S]
    const float* enc_in  = (const float*)d_in[1];  // [2048,1024]
    const float* dec_in  = (const float*)d_in[2];  // [1024,1024]
    const float* ibias   = (const float*)d_in[3];  // [B,S]
    const float* W       = (const float*)d_in[4];  // [1024,1024]
    const float* bproj   = (const float*)d_in[5];  // [1024]
    float* out = (float*)d_out;

    // scores split-K partials (read by scatter while d_out is being zeroed) -> ws: 8 MB
    float* scores = (float*)d_ws;                  // 4 x [4,256,512] fp32

    // all other intermediates live in the dead tail of d_out (zeroed by the
    // tail-row scatter blocks last)
    size_t outBytes = (size_t)out_size * sizeof(float);
    char* tail = (char*)d_out + outBytes - (size_t)12 * 1024 * 1024;
    unsigned short* Aeh = (unsigned short*)tail;        // enc_in fp16 [2048,1024] 4 MB
    unsigned short* Dh  = Aeh + (size_t)2048 * 1024;    // dec fp16    [1024,1024] 2 MB
    unsigned short* Wth = Dh  + (size_t)1024 * 1024;    // W^T fp16    [1024,1024] 2 MB
    unsigned short* ench = Wth + (size_t)1024 * 1024;   // tanh out    [2048,1024] 4 MB

    // 1) merged prep: converts + W transpose
    prep<<<dim3(3328), 256, 0, stream>>>(enc_in, Aeh, dec_in, Dh, W, Wth);

    // 2) enc = tanh(enc_in @ W + bproj) -> fp16, + zero d_out rows [0,925)
    gemm_f16<1><<<dim3(16, 32, 1), 256, 0, stream>>>(
        Aeh, Wth, bproj, nullptr, ench, (f32x4*)d_out,
        1024, 1024, 16, 1, 0LL, 0LL, 0LL, 0LL);

    // 3) scores[b] = dec[b] @ enc[b]^T   per batch M=256,N=512,K=1024, split-K=4
    gemm_f16<0><<<dim3(8, 4, 16), 256, 0, stream>>>(
        Dh, ench, nullptr, scores, nullptr, nullptr,
        512, 1024, 4, 4,
        (long long)256 * 1024, (long long)512 * 1024,
        (long long)256 * 512, (long long)4 * 256 * 512);

    // 4) sum parts + bias, softmax over S, zero tail rows, scatter-add
    softmax_scatter<<<dim3(4 * 256), 256, 0, stream>>>(scores, inputs, ibias, out);
}

// Round 11
// 198.939 us; speedup vs baseline: 1.1703x; 1.1703x over previous
//
#include <hip/hip_runtime.h>
#include <hip/hip_bf16.h>
#include <math.h>

// Dims fixed by setup_inputs: B=4, S=512, T=256, H=1024, V=32000
// Pure single-fp16 operands; r8 measured absmax 0.0078 < 0.02.
// r11 = r8 revert (no zero-interleave: vmcnt-counted stores in a barriered
// K-loop serialize the drain -- r10 lesson) + gemm1 64x128 tile:
// staged bytes 128->96 MB at 256 blocks.
typedef _Float16 f16x8 __attribute__((ext_vector_type(8)));
typedef float    f32x4 __attribute__((ext_vector_type(4)));

__device__ __forceinline__ unsigned short h2us(_Float16 v) {
    return *(unsigned short*)&v;
}

// async global->LDS, 16B per lane; LDS dest = wave-uniform base + lane*16
__device__ __forceinline__ void gl2lds16(const void* g, void* l) {
    __builtin_amdgcn_global_load_lds(
        (const __attribute__((address_space(1))) unsigned int*)(uintptr_t)g,
        (__attribute__((address_space(3))) unsigned int*)(unsigned int)(uintptr_t)l,
        16, 0, 0);
}

// ---- merged prep: fp32->fp16 (enc_in, dec_in) + W transpose->fp16 ----
__global__ __launch_bounds__(256) void prep(const float* __restrict__ encf,
                                            unsigned short* __restrict__ eh,
                                            const float* __restrict__ decf,
                                            unsigned short* __restrict__ dh,
                                            const float* __restrict__ W,
                                            unsigned short* __restrict__ Wth) {
    const int bid = blockIdx.x;
    if (bid < 3072) {
        const float* src; unsigned short* ph; int i;
        if (bid < 2048) { src = encf; ph = eh; i = bid * 256 + threadIdx.x; }
        else            { src = decf; ph = dh; i = (bid - 2048) * 256 + threadIdx.x; }
        const float4 v = ((const float4*)src)[i];
        ushort4 h;
        h.x = h2us((_Float16)v.x);
        h.y = h2us((_Float16)v.y);
        h.z = h2us((_Float16)v.z);
        h.w = h2us((_Float16)v.w);
        ((ushort4*)ph)[i] = h;
        return;
    }
    // transpose+convert W: Wt[n][k] = fp16(W[k][n])
    __shared__ float tile[64][65];
    const int tb = bid - 3072;
    const int k0 = (tb >> 4) * 64, n0 = (tb & 15) * 64;
    const int c = threadIdx.x & 63, r0 = threadIdx.x >> 6;
    #pragma unroll
    for (int p = 0; p < 16; ++p) {
        int r = r0 + p * 4;
        tile[r][c] = W[(size_t)(k0 + r) * 1024 + n0 + c];
    }
    __syncthreads();
    #pragma unroll
    for (int p = 0; p < 16; ++p) {
        int rn = r0 + p * 4;
        float v = tile[c][rn];               // = W[k0+c][n0+rn]
        Wth[(size_t)(n0 + rn) * 1024 + k0 + c] = h2us((_Float16)v);
    }
}

// ---- gemm1: 64x128 tile, BK=64, enc = tanh(A @ W^T' + bias) -> fp16 ----
// A [2048,1024] fp16, B = W^T [1024,1024] fp16 ([N][K]).
// 4 waves: wm=row-half(32), wn=col-half(64); acc[2][4] of 16x16x32.
// Staged/block: A 128KB + B 256KB; 256 blocks -> 96 MB total.
__global__ __launch_bounds__(256) void gemm1_wide(
    const unsigned short* __restrict__ Ah,
    const unsigned short* __restrict__ Bh,
    const float* __restrict__ bias,
    unsigned short* __restrict__ Ch) {
    const int K = 1024, N = 1024;
    __shared__ __align__(16) unsigned short sAh[64 * 64];    // 8 KB
    __shared__ __align__(16) unsigned short sBh[128 * 64];   // 16 KB

    const int t = threadIdx.x;
    const int lane = t & 63;
    const int w = t >> 6;
    const int wm = w >> 1, wn = w & 1;
    const int ln15 = lane & 15, q4 = lane >> 4;

    const int row0 = blockIdx.y * 64;
    const int col0 = blockIdx.x * 128;

    // A: 512 16B-chunks, thread covers {t, t+256}; swizzle g = (c&7)^(r&7)
    const int c0 = t,       r0s = c0 >> 3, g0 = ((c0 & 7) ^ (r0s & 7)) * 8;
    const int c1 = t + 256, r1s = c1 >> 3, g1 = ((c1 & 7) ^ (r1s & 7)) * 8;
    const size_t a0 = (size_t)(row0 + r0s) * K + g0;
    const size_t a1 = (size_t)(row0 + r1s) * K + g1;
    // B: 1024 chunks, thread covers {t, +256, +512, +768}
    size_t bo[4]; int bc[4];
    #pragma unroll
    for (int u = 0; u < 4; ++u) {
        int c = t + u * 256;
        int r = c >> 3, g = ((c & 7) ^ (r & 7)) * 8;
        bo[u] = (size_t)(col0 + r) * K + g;
        bc[u] = c;
    }

    f32x4 acc[2][4] = {};

    for (int kk = 0; kk < 16; ++kk) {
        const int k0 = kk * 64;
        gl2lds16(Ah + a0 + k0, &sAh[c0 * 8]);
        gl2lds16(Ah + a1 + k0, &sAh[c1 * 8]);
        #pragma unroll
        for (int u = 0; u < 4; ++u)
            gl2lds16(Bh + bo[u] + k0, &sBh[bc[u] * 8]);
        __syncthreads();

        #pragma unroll
        for (int kh = 0; kh < 2; ++kh) {
            f16x8 ah[2], bh[4];
            #pragma unroll
            for (int i = 0; i < 2; ++i) {
                int rr = wm * 32 + i * 16 + ln15;
                ah[i] = *(const f16x8*)&sAh[rr * 64 + (((kh * 4 + q4) ^ (rr & 7)) * 8)];
            }
            #pragma unroll
            for (int j = 0; j < 4; ++j) {
                int rr = wn * 64 + j * 16 + ln15;
                bh[j] = *(const f16x8*)&sBh[rr * 64 + (((kh * 4 + q4) ^ (rr & 7)) * 8)];
            }
            #pragma unroll
            for (int i = 0; i < 2; ++i)
                #pragma unroll
                for (int j = 0; j < 4; ++j)
                    acc[i][j] = __builtin_amdgcn_mfma_f32_16x16x32_f16(ah[i], bh[j], acc[i][j], 0, 0, 0);
        }
        __syncthreads();
    }

    // epilogue: C layout col=lane&15, row=(lane>>4)*4+reg
    #pragma unroll
    for (int i = 0; i < 2; ++i)
        #pragma unroll
        for (int j = 0; j < 4; ++j) {
            int colg = col0 + wn * 64 + j * 16 + ln15;
            float bv = bias[colg];
            #pragma unroll
            for (int r = 0; r < 4; ++r) {
                int rowg = row0 + wm * 32 + i * 16 + q4 * 4 + r;
                _Float16 h = (_Float16)tanhf(acc[i][j][r] + bv);
                Ch[(size_t)rowg * N + colg] = h2us(h);
            }
        }
}

// ---- gemm2: 64x64 tile, BK=64, split-K fp32 partials (r8-proven) ----
__global__ __launch_bounds__(256) void gemm2_f16(
    const unsigned short* __restrict__ Ah,
    const unsigned short* __restrict__ Bh,
    float* __restrict__ Cf,
    int N, int K, int kIter, int ksplit,
    long long aBatch, long long bBatch, long long cBatch, long long cPart) {

    const int z = blockIdx.z;
    const int batch = z / ksplit;
    const int ks = z - batch * ksplit;
    Ah += (size_t)batch * aBatch;
    Bh += (size_t)batch * bBatch;
    const int kOff = ks * kIter * 64;

    __shared__ __align__(16) unsigned short sAh[64 * 64];
    __shared__ __align__(16) unsigned short sBh[64 * 64];

    const int t = threadIdx.x;
    const int lane = t & 63;
    const int w = t >> 6;
    const int wm = w >> 1, wn = w & 1;
    const int ln15 = lane & 15, q4 = lane >> 4;

    const int row0 = blockIdx.y * 64;
    const int col0 = blockIdx.x * 64;

    const int c0 = w * 128 + lane;
    const int r0s = c0 >> 3, g0 = ((c0 & 7) ^ (r0s & 7)) * 8;
    const int c1 = c0 + 64;
    const int r1s = c1 >> 3, g1 = ((c1 & 7) ^ (r1s & 7)) * 8;
    const size_t a0 = (size_t)(row0 + r0s) * K + kOff + g0;
    const size_t a1 = (size_t)(row0 + r1s) * K + kOff + g1;
    const size_t b0 = (size_t)(col0 + r0s) * K + kOff + g0;
    const size_t b1 = (size_t)(col0 + r1s) * K + kOff + g1;

    f32x4 acc[2][2] = {};

    for (int kk = 0; kk < kIter; ++kk) {
        const int k0 = kk * 64;
        gl2lds16(Ah + a0 + k0, &sAh[c0 * 8]);
        gl2lds16(Ah + a1 + k0, &sAh[c1 * 8]);
        gl2lds16(Bh + b0 + k0, &sBh[c0 * 8]);
        gl2lds16(Bh + b1 + k0, &sBh[c1 * 8]);
        __syncthreads();

        #pragma unroll
        for (int kh = 0; kh < 2; ++kh) {
            f16x8 ah[2], bh[2];
            #pragma unroll
            for (int i = 0; i < 2; ++i) {
                int rr = wm * 32 + i * 16 + ln15;
                ah[i] = *(const f16x8*)&sAh[rr * 64 + (((kh * 4 + q4) ^ (rr & 7)) * 8)];
            }
            #pragma unroll
            for (int j = 0; j < 2; ++j) {
                int rr = wn * 32 + j * 16 + ln15;
                bh[j] = *(const f16x8*)&sBh[rr * 64 + (((kh * 4 + q4) ^ (rr & 7)) * 8)];
            }
            #pragma unroll
            for (int i = 0; i < 2; ++i)
                #pragma unroll
                for (int j = 0; j < 2; ++j)
                    acc[i][j] = __builtin_amdgcn_mfma_f32_16x16x32_f16(ah[i], bh[j], acc[i][j], 0, 0, 0);
        }
        __syncthreads();
    }

    float* outp = Cf + (size_t)batch * cBatch + (size_t)ks * cPart;
    #pragma unroll
    for (int i = 0; i < 2; ++i)
        #pragma unroll
        for (int j = 0; j < 2; ++j) {
            int colg = col0 + wn * 32 + j * 16 + ln15;
            #pragma unroll
            for (int r = 0; r < 4; ++r) {
                int rowg = row0 + wm * 32 + i * 16 + q4 * 4 + r;
                outp[(size_t)rowg * N + colg] = acc[i][j][r];
            }
        }
}

// ---- fused: sum 4 split-K parts + bias, softmax over S, zero vocab row, scatter ----
__inline__ __device__ float waveReduceMax(float v) {
    #pragma unroll
    for (int off = 32; off > 0; off >>= 1) v = fmaxf(v, __shfl_down(v, off));
    return v;
}
__inline__ __device__ float waveReduceSum(float v) {
    #pragma unroll
    for (int off = 32; off > 0; off >>= 1) v += __shfl_down(v, off);
    return v;
}

__global__ __launch_bounds__(256) void softmax_scatter(const float* __restrict__ scores,
                                                       const int* __restrict__ tokens,
                                                       const float* __restrict__ ibias,
                                                       float* __restrict__ out) {
    const int row = blockIdx.x;          // b*T + t
    const int b = row >> 8;              // T = 256
    const size_t plane = (size_t)4 * 256 * 512;
    const float* s0 = scores + (size_t)row * 512;
    const float* bi = ibias + (size_t)b * 512;
    const int* tok = tokens + (size_t)b * 512;
    float* o = out + (size_t)row * 32000;

    __shared__ float red[4];
    const int tid = threadIdx.x;
    const int wid = tid >> 6, lane = tid & 63;

    float v0 = bi[tid], v1 = bi[tid + 256];
    #pragma unroll
    for (int p = 0; p < 4; ++p) {
        v0 += s0[p * plane + tid];
        v1 += s0[p * plane + tid + 256];
    }

    float m = fmaxf(v0, v1);
    m = waveReduceMax(m);
    if (lane == 0) red[wid] = m;
    __syncthreads();
    if (tid == 0) red[0] = fmaxf(fmaxf(red[0], red[1]), fmaxf(red[2], red[3]));
    __syncthreads();
    const float rowmax = red[0];
    __syncthreads();

    float e0 = __expf(v0 - rowmax);
    float e1 = __expf(v1 - rowmax);
    float s = e0 + e1;
    s = waveReduceSum(s);
    if (lane == 0) red[wid] = s;
    __syncthreads();
    if (tid == 0) red[0] = red[0] + red[1] + red[2] + red[3];
    __syncthreads();
    const float inv = 1.0f / red[0];

    // zero this row's 32000 vocab slots (row exclusive to this block)
    float4 z = make_float4(0.f, 0.f, 0.f, 0.f);
    float4* o4 = (float4*)o;
    for (int i = tid; i < 8000; i += 256) o4[i] = z;

    __threadfence_block();
    __syncthreads();

    atomicAdd(&o[tok[tid]],       e0 * inv);
    atomicAdd(&o[tok[tid + 256]], e1 * inv);
}

extern "C" void kernel_launch(void* const* d_in, const int* in_sizes, int n_in,
                              void* d_out, int out_size, void* d_ws, size_t ws_size,
                              hipStream_t stream) {
    const int*   inputs  = (const int*)d_in[0];    // [B,S]
    const float* enc_in  = (const float*)d_in[1];  // [2048,1024]
    const float* dec_in  = (const float*)d_in[2];  // [1024,1024]
    const float* ibias   = (const float*)d_in[3];  // [B,S]
    const float* W       = (const float*)d_in[4];  // [1024,1024]
    const float* bproj   = (const float*)d_in[5];  // [1024]
    float* out = (float*)d_out;

    // scores split-K partials (read by scatter while d_out is being zeroed) -> ws: 8 MB
    float* scores = (float*)d_ws;                  // 4 x [4,256,512] fp32

    // all other intermediates live in the dead tail of d_out (zeroed by scatter last)
    size_t outBytes = (size_t)out_size * sizeof(float);
    char* tail = (char*)d_out + outBytes - (size_t)12 * 1024 * 1024;
    unsigned short* Aeh = (unsigned short*)tail;        // enc_in fp16 [2048,1024] 4 MB
    unsigned short* Dh  = Aeh + (size_t)2048 * 1024;    // dec fp16    [1024,1024] 2 MB
    unsigned short* Wth = Dh  + (size_t)1024 * 1024;    // W^T fp16    [1024,1024] 2 MB
    unsigned short* ench = Wth + (size_t)1024 * 1024;   // tanh out    [2048,1024] 4 MB

    // 1) merged prep: converts + W transpose
    prep<<<dim3(3328), 256, 0, stream>>>(enc_in, Aeh, dec_in, Dh, W, Wth);

    // 2) enc = tanh(enc_in @ W + bproj) -> fp16   M=2048,N=1024,K=1024
    //    64x128 tile -> grid (8,32) = 256 blocks, 96 MB staged
    gemm1_wide<<<dim3(8, 32), 256, 0, stream>>>(Aeh, Wth, bproj, ench);

    // 3) scores[b] = dec[b] @ enc[b]^T   per batch M=256,N=512,K=1024, split-K=4
    gemm2_f16<<<dim3(8, 4, 16), 256, 0, stream>>>(
        Dh, ench, scores,
        512, 1024, 4, 4,
        (long long)256 * 1024, (long long)512 * 1024,
        (long long)256 * 512, (long long)4 * 256 * 512);

    // 4) sum parts + bias, softmax over S, zero vocab row, scatter-add
    softmax_scatter<<<dim3(4 * 256), 256, 0, stream>>>(scores, inputs, ibias, out);
}

// Round 12
// 197.208 us; speedup vs baseline: 1.1806x; 1.0088x over previous
//
#include <hip/hip_runtime.h>
#include <hip/hip_bf16.h>
#include <math.h>

// Dims fixed by setup_inputs: B=4, S=512, T=256, H=1024, V=32000
// r12 = r8 (best, 193.9 us) + scatter zero-store hoist.
// Pure single-fp16 operands; measured absmax 0.0078 < 0.02 threshold.
// Geometry lessons (r4-r11): 64x64 tile / 512 blocks (2 blocks/CU) is the
// constrained optimum -- square tile minimizes staged bytes at fixed block
// count; >= 2 blocks/CU needed for barrier-drain overlap. No NT stores
// (r10: degrades harness fill); no vmcnt-counted stores inside the K-loop.
typedef _Float16 f16x8 __attribute__((ext_vector_type(8)));
typedef float    f32x4 __attribute__((ext_vector_type(4)));

__device__ __forceinline__ unsigned short h2us(_Float16 v) {
    return *(unsigned short*)&v;
}

// async global->LDS, 16B per lane; LDS dest = wave-uniform base + lane*16
__device__ __forceinline__ void gl2lds16(const void* g, void* l) {
    __builtin_amdgcn_global_load_lds(
        (const __attribute__((address_space(1))) unsigned int*)(uintptr_t)g,
        (__attribute__((address_space(3))) unsigned int*)(unsigned int)(uintptr_t)l,
        16, 0, 0);
}

// ---- merged prep: fp32->fp16 (enc_in, dec_in) + W transpose->fp16 ----
__global__ __launch_bounds__(256) void prep(const float* __restrict__ encf,
                                            unsigned short* __restrict__ eh,
                                            const float* __restrict__ decf,
                                            unsigned short* __restrict__ dh,
                                            const float* __restrict__ W,
                                            unsigned short* __restrict__ Wth) {
    const int bid = blockIdx.x;
    if (bid < 3072) {
        const float* src; unsigned short* ph; int i;
        if (bid < 2048) { src = encf; ph = eh; i = bid * 256 + threadIdx.x; }
        else            { src = decf; ph = dh; i = (bid - 2048) * 256 + threadIdx.x; }
        const float4 v = ((const float4*)src)[i];
        ushort4 h;
        h.x = h2us((_Float16)v.x);
        h.y = h2us((_Float16)v.y);
        h.z = h2us((_Float16)v.z);
        h.w = h2us((_Float16)v.w);
        ((ushort4*)ph)[i] = h;
        return;
    }
    // transpose+convert W: Wt[n][k] = fp16(W[k][n])
    __shared__ float tile[64][65];
    const int tb = bid - 3072;
    const int k0 = (tb >> 4) * 64, n0 = (tb & 15) * 64;
    const int c = threadIdx.x & 63, r0 = threadIdx.x >> 6;
    #pragma unroll
    for (int p = 0; p < 16; ++p) {
        int r = r0 + p * 4;
        tile[r][c] = W[(size_t)(k0 + r) * 1024 + n0 + c];
    }
    __syncthreads();
    #pragma unroll
    for (int p = 0; p < 16; ++p) {
        int rn = r0 + p * 4;
        float v = tile[c][rn];               // = W[k0+c][n0+rn]
        Wth[(size_t)(n0 + rn) * 1024 + k0 + c] = h2us((_Float16)v);
    }
}

// ---- fp16 MFMA GEMM, 64x64 tile, BK=64, B^T [N][K], single-fp16 A and B.
// Staging via global_load_lds(16B), XOR-swizzled LDS k-chunks.
// EPI 0: fp32 partials (split-K). EPI 1: tanh(acc+bias[n]) -> single fp16.
template <int EPI>
__global__ __launch_bounds__(256) void gemm_f16(
    const unsigned short* __restrict__ Ah,
    const unsigned short* __restrict__ Bh,
    const float* __restrict__ bias,
    float* __restrict__ Cf, unsigned short* __restrict__ Ch,
    int N, int K, int kIter, int ksplit,
    long long aBatch, long long bBatch, long long cBatch, long long cPart) {

    const int z = blockIdx.z;
    const int batch = z / ksplit;
    const int ks = z - batch * ksplit;
    Ah += (size_t)batch * aBatch;
    Bh += (size_t)batch * bBatch;
    const int kOff = ks * kIter * 64;

    __shared__ __align__(16) unsigned short sAh[64 * 64];
    __shared__ __align__(16) unsigned short sBh[64 * 64];

    const int t = threadIdx.x;
    const int lane = t & 63;
    const int w = t >> 6;
    const int wm = w >> 1, wn = w & 1;
    const int ln15 = lane & 15, q4 = lane >> 4;

    const int row0 = blockIdx.y * 64;
    const int col0 = blockIdx.x * 64;

    // staging: 512 16B-chunks per array; wave w pass p covers chunks w*128+p*64+lane.
    // LDS chunk (r, ch) holds global k-chunk (ch ^ (r&7))  [bank swizzle]
    const int c0 = w * 128 + lane;
    const int r0s = c0 >> 3, g0 = ((c0 & 7) ^ (r0s & 7)) * 8;
    const int c1 = c0 + 64;
    const int r1s = c1 >> 3, g1 = ((c1 & 7) ^ (r1s & 7)) * 8;
    const size_t a0 = (size_t)(row0 + r0s) * K + kOff + g0;
    const size_t a1 = (size_t)(row0 + r1s) * K + kOff + g1;
    const size_t b0 = (size_t)(col0 + r0s) * K + kOff + g0;
    const size_t b1 = (size_t)(col0 + r1s) * K + kOff + g1;

    f32x4 acc[2][2] = {};

    for (int kk = 0; kk < kIter; ++kk) {
        const int k0 = kk * 64;
        gl2lds16(Ah + a0 + k0, &sAh[c0 * 8]);
        gl2lds16(Ah + a1 + k0, &sAh[c1 * 8]);
        gl2lds16(Bh + b0 + k0, &sBh[c0 * 8]);
        gl2lds16(Bh + b1 + k0, &sBh[c1 * 8]);
        __syncthreads();

        #pragma unroll
        for (int kh = 0; kh < 2; ++kh) {
            f16x8 ah[2], bh[2];
            #pragma unroll
            for (int i = 0; i < 2; ++i) {
                int rr = wm * 32 + i * 16 + ln15;
                int off = rr * 64 + (((kh * 4 + q4) ^ (rr & 7)) * 8);
                ah[i] = *(const f16x8*)&sAh[off];
            }
            #pragma unroll
            for (int j = 0; j < 2; ++j) {
                int rr = wn * 32 + j * 16 + ln15;
                int off = rr * 64 + (((kh * 4 + q4) ^ (rr & 7)) * 8);
                bh[j] = *(const f16x8*)&sBh[off];
            }
            #pragma unroll
            for (int i = 0; i < 2; ++i)
                #pragma unroll
                for (int j = 0; j < 2; ++j)
                    acc[i][j] = __builtin_amdgcn_mfma_f32_16x16x32_f16(ah[i], bh[j], acc[i][j], 0, 0, 0);
        }
        __syncthreads();
    }

    // epilogue: C layout col=lane&15, row=(lane>>4)*4+reg
    float* outp = (EPI == 0) ? (Cf + (size_t)batch * cBatch + (size_t)ks * cPart) : nullptr;
    #pragma unroll
    for (int i = 0; i < 2; ++i)
        #pragma unroll
        for (int j = 0; j < 2; ++j) {
            int colg = col0 + wn * 32 + j * 16 + ln15;
            float bv = (EPI == 1) ? bias[colg] : 0.0f;
            #pragma unroll
            for (int r = 0; r < 4; ++r) {
                int rowg = row0 + wm * 32 + i * 16 + q4 * 4 + r;
                if (EPI == 0) {
                    outp[(size_t)rowg * N + colg] = acc[i][j][r];
                } else {
                    _Float16 h = (_Float16)tanhf(acc[i][j][r] + bv);
                    Ch[(size_t)rowg * N + colg] = h2us(h);
                }
            }
        }
}

// ---- fused: zero vocab row (hoisted first, overlaps reductions),
//      sum 4 split-K parts + bias, softmax over S, scatter ----
__inline__ __device__ float waveReduceMax(float v) {
    #pragma unroll
    for (int off = 32; off > 0; off >>= 1) v = fmaxf(v, __shfl_down(v, off));
    return v;
}
__inline__ __device__ float waveReduceSum(float v) {
    #pragma unroll
    for (int off = 32; off > 0; off >>= 1) v += __shfl_down(v, off);
    return v;
}

__global__ __launch_bounds__(256) void softmax_scatter(const float* __restrict__ scores,
                                                       const int* __restrict__ tokens,
                                                       const float* __restrict__ ibias,
                                                       float* __restrict__ out) {
    const int row = blockIdx.x;          // b*T + t
    const int b = row >> 8;              // T = 256
    const size_t plane = (size_t)4 * 256 * 512;
    const float* s0 = scores + (size_t)row * 512;
    const float* bi = ibias + (size_t)b * 512;
    const int* tok = tokens + (size_t)b * 512;
    float* o = out + (size_t)row * 32000;

    __shared__ float red[4];
    const int tid = threadIdx.x;
    const int wid = tid >> 6, lane = tid & 63;

    // issue the 131 MB/grid zero-stores FIRST so they drain while the
    // softmax reductions below wait on loads/barriers (row is block-exclusive)
    {
        float4 z = make_float4(0.f, 0.f, 0.f, 0.f);
        float4* o4 = (float4*)o;
        #pragma unroll 4
        for (int i = tid; i < 8000; i += 256) o4[i] = z;
    }

    float v0 = bi[tid], v1 = bi[tid + 256];
    #pragma unroll
    for (int p = 0; p < 4; ++p) {
        v0 += s0[p * plane + tid];
        v1 += s0[p * plane + tid + 256];
    }

    float m = fmaxf(v0, v1);
    m = waveReduceMax(m);
    if (lane == 0) red[wid] = m;
    __syncthreads();
    if (tid == 0) red[0] = fmaxf(fmaxf(red[0], red[1]), fmaxf(red[2], red[3]));
    __syncthreads();
    const float rowmax = red[0];
    __syncthreads();

    float e0 = __expf(v0 - rowmax);
    float e1 = __expf(v1 - rowmax);
    float s = e0 + e1;
    s = waveReduceSum(s);
    if (lane == 0) red[wid] = s;
    __syncthreads();
    if (tid == 0) red[0] = red[0] + red[1] + red[2] + red[3];
    __syncthreads();
    const float inv = 1.0f / red[0];

    // ensure all zero-stores (any thread) are complete before atomics:
    // __syncthreads implies vmcnt(0) drain on gfx950
    __syncthreads();

    atomicAdd(&o[tok[tid]],       e0 * inv);
    atomicAdd(&o[tok[tid + 256]], e1 * inv);
}

extern "C" void kernel_launch(void* const* d_in, const int* in_sizes, int n_in,
                              void* d_out, int out_size, void* d_ws, size_t ws_size,
                              hipStream_t stream) {
    const int*   inputs  = (const int*)d_in[0];    // [B,S]
    const float* enc_in  = (const float*)d_in[1];  // [2048,1024]
    const float* dec_in  = (const float*)d_in[2];  // [1024,1024]
    const float* ibias   = (const float*)d_in[3];  // [B,S]
    const float* W       = (const float*)d_in[4];  // [1024,1024]
    const float* bproj   = (const float*)d_in[5];  // [1024]
    float* out = (float*)d_out;

    // scores split-K partials (read by scatter while d_out is being zeroed) -> ws: 8 MB
    float* scores = (float*)d_ws;                  // 4 x [4,256,512] fp32

    // all other intermediates live in the dead tail of d_out (zeroed by scatter last)
    size_t outBytes = (size_t)out_size * sizeof(float);
    char* tail = (char*)d_out + outBytes - (size_t)12 * 1024 * 1024;
    unsigned short* Aeh = (unsigned short*)tail;        // enc_in fp16 [2048,1024] 4 MB
    unsigned short* Dh  = Aeh + (size_t)2048 * 1024;    // dec fp16    [1024,1024] 2 MB
    unsigned short* Wth = Dh  + (size_t)1024 * 1024;    // W^T fp16    [1024,1024] 2 MB
    unsigned short* ench = Wth + (size_t)1024 * 1024;   // tanh out    [2048,1024] 4 MB

    // 1) merged prep: converts + W transpose
    prep<<<dim3(3328), 256, 0, stream>>>(enc_in, Aeh, dec_in, Dh, W, Wth);

    // 2) enc = tanh(enc_in @ W + bproj) -> fp16   M=2048,N=1024,K=1024
    gemm_f16<1><<<dim3(16, 32, 1), 256, 0, stream>>>(
        Aeh, Wth, bproj, nullptr, ench,
        1024, 1024, 16, 1, 0LL, 0LL, 0LL, 0LL);

    // 3) scores[b] = dec[b] @ enc[b]^T   per batch M=256,N=512,K=1024, split-K=4
    gemm_f16<0><<<dim3(8, 4, 16), 256, 0, stream>>>(
        Dh, ench, nullptr, scores, nullptr,
        512, 1024, 4, 4,
        (long long)256 * 1024, (long long)512 * 1024,
        (long long)256 * 512, (long long)4 * 256 * 512);

    // 4) zero vocab rows (hoisted) + sum parts + bias + softmax + scatter-add
    softmax_scatter<<<dim3(4 * 256), 256, 0, stream>>>(scores, inputs, ibias, out);
}

// Round 13
// 194.011 us; speedup vs baseline: 1.2001x; 1.0165x over previous
//
#include <hip/hip_runtime.h>
#include <hip/hip_bf16.h>
#include <math.h>

// Dims fixed by setup_inputs: B=4, S=512, T=256, H=1024, V=32000
// FINAL (= r8, session best 193.9 us). Pure single-fp16 operands;
// measured absmax 0.0078 < 0.02 threshold.
// Converged geometry (r4-r12 evidence):
//  - 64x64 tile / BK=64 / 512 blocks (2 blocks/CU): square tile minimizes
//    staged operand bytes; >=2 blocks/CU required for barrier-drain overlap
//    (r5/r11 cliffs at 1 block/CU).
//  - GEMM time ~= staged bytes / ~6-7.6 TB/s (per-CU load-path limit);
//    split-K/occupancy/direct-from-L2 variants don't move it (r4/r6).
//  - Zero-fill lives AFTER the softmax reductions (r10: NT/vmcnt stores in
//    barriered K-loop serialize; r12: hoist-before-loads delays reductions).
typedef _Float16 f16x8 __attribute__((ext_vector_type(8)));
typedef float    f32x4 __attribute__((ext_vector_type(4)));

__device__ __forceinline__ unsigned short h2us(_Float16 v) {
    return *(unsigned short*)&v;
}

// async global->LDS, 16B per lane; LDS dest = wave-uniform base + lane*16
__device__ __forceinline__ void gl2lds16(const void* g, void* l) {
    __builtin_amdgcn_global_load_lds(
        (const __attribute__((address_space(1))) unsigned int*)(uintptr_t)g,
        (__attribute__((address_space(3))) unsigned int*)(unsigned int)(uintptr_t)l,
        16, 0, 0);
}

// ---- merged prep: fp32->fp16 (enc_in, dec_in) + W transpose->fp16 ----
__global__ __launch_bounds__(256) void prep(const float* __restrict__ encf,
                                            unsigned short* __restrict__ eh,
                                            const float* __restrict__ decf,
                                            unsigned short* __restrict__ dh,
                                            const float* __restrict__ W,
                                            unsigned short* __restrict__ Wth) {
    const int bid = blockIdx.x;
    if (bid < 3072) {
        const float* src; unsigned short* ph; int i;
        if (bid < 2048) { src = encf; ph = eh; i = bid * 256 + threadIdx.x; }
        else            { src = decf; ph = dh; i = (bid - 2048) * 256 + threadIdx.x; }
        const float4 v = ((const float4*)src)[i];
        ushort4 h;
        h.x = h2us((_Float16)v.x);
        h.y = h2us((_Float16)v.y);
        h.z = h2us((_Float16)v.z);
        h.w = h2us((_Float16)v.w);
        ((ushort4*)ph)[i] = h;
        return;
    }
    // transpose+convert W: Wt[n][k] = fp16(W[k][n])
    __shared__ float tile[64][65];
    const int tb = bid - 3072;
    const int k0 = (tb >> 4) * 64, n0 = (tb & 15) * 64;
    const int c = threadIdx.x & 63, r0 = threadIdx.x >> 6;
    #pragma unroll
    for (int p = 0; p < 16; ++p) {
        int r = r0 + p * 4;
        tile[r][c] = W[(size_t)(k0 + r) * 1024 + n0 + c];
    }
    __syncthreads();
    #pragma unroll
    for (int p = 0; p < 16; ++p) {
        int rn = r0 + p * 4;
        float v = tile[c][rn];               // = W[k0+c][n0+rn]
        Wth[(size_t)(n0 + rn) * 1024 + k0 + c] = h2us((_Float16)v);
    }
}

// ---- fp16 MFMA GEMM, 64x64 tile, BK=64, B^T [N][K], single-fp16 A and B.
// Staging via global_load_lds(16B), XOR-swizzled LDS k-chunks.
// EPI 0: fp32 partials (split-K). EPI 1: tanh(acc+bias[n]) -> single fp16.
template <int EPI>
__global__ __launch_bounds__(256) void gemm_f16(
    const unsigned short* __restrict__ Ah,
    const unsigned short* __restrict__ Bh,
    const float* __restrict__ bias,
    float* __restrict__ Cf, unsigned short* __restrict__ Ch,
    int N, int K, int kIter, int ksplit,
    long long aBatch, long long bBatch, long long cBatch, long long cPart) {

    const int z = blockIdx.z;
    const int batch = z / ksplit;
    const int ks = z - batch * ksplit;
    Ah += (size_t)batch * aBatch;
    Bh += (size_t)batch * bBatch;
    const int kOff = ks * kIter * 64;

    __shared__ __align__(16) unsigned short sAh[64 * 64];
    __shared__ __align__(16) unsigned short sBh[64 * 64];

    const int t = threadIdx.x;
    const int lane = t & 63;
    const int w = t >> 6;
    const int wm = w >> 1, wn = w & 1;
    const int ln15 = lane & 15, q4 = lane >> 4;

    const int row0 = blockIdx.y * 64;
    const int col0 = blockIdx.x * 64;

    // staging: 512 16B-chunks per array; wave w pass p covers chunks w*128+p*64+lane.
    // LDS chunk (r, ch) holds global k-chunk (ch ^ (r&7))  [bank swizzle]
    const int c0 = w * 128 + lane;
    const int r0s = c0 >> 3, g0 = ((c0 & 7) ^ (r0s & 7)) * 8;
    const int c1 = c0 + 64;
    const int r1s = c1 >> 3, g1 = ((c1 & 7) ^ (r1s & 7)) * 8;
    const size_t a0 = (size_t)(row0 + r0s) * K + kOff + g0;
    const size_t a1 = (size_t)(row0 + r1s) * K + kOff + g1;
    const size_t b0 = (size_t)(col0 + r0s) * K + kOff + g0;
    const size_t b1 = (size_t)(col0 + r1s) * K + kOff + g1;

    f32x4 acc[2][2] = {};

    for (int kk = 0; kk < kIter; ++kk) {
        const int k0 = kk * 64;
        gl2lds16(Ah + a0 + k0, &sAh[c0 * 8]);
        gl2lds16(Ah + a1 + k0, &sAh[c1 * 8]);
        gl2lds16(Bh + b0 + k0, &sBh[c0 * 8]);
        gl2lds16(Bh + b1 + k0, &sBh[c1 * 8]);
        __syncthreads();

        #pragma unroll
        for (int kh = 0; kh < 2; ++kh) {
            f16x8 ah[2], bh[2];
            #pragma unroll
            for (int i = 0; i < 2; ++i) {
                int rr = wm * 32 + i * 16 + ln15;
                int off = rr * 64 + (((kh * 4 + q4) ^ (rr & 7)) * 8);
                ah[i] = *(const f16x8*)&sAh[off];
            }
            #pragma unroll
            for (int j = 0; j < 2; ++j) {
                int rr = wn * 32 + j * 16 + ln15;
                int off = rr * 64 + (((kh * 4 + q4) ^ (rr & 7)) * 8);
                bh[j] = *(const f16x8*)&sBh[off];
            }
            #pragma unroll
            for (int i = 0; i < 2; ++i)
                #pragma unroll
                for (int j = 0; j < 2; ++j)
                    acc[i][j] = __builtin_amdgcn_mfma_f32_16x16x32_f16(ah[i], bh[j], acc[i][j], 0, 0, 0);
        }
        __syncthreads();
    }

    // epilogue: C layout col=lane&15, row=(lane>>4)*4+reg
    float* outp = (EPI == 0) ? (Cf + (size_t)batch * cBatch + (size_t)ks * cPart) : nullptr;
    #pragma unroll
    for (int i = 0; i < 2; ++i)
        #pragma unroll
        for (int j = 0; j < 2; ++j) {
            int colg = col0 + wn * 32 + j * 16 + ln15;
            float bv = (EPI == 1) ? bias[colg] : 0.0f;
            #pragma unroll
            for (int r = 0; r < 4; ++r) {
                int rowg = row0 + wm * 32 + i * 16 + q4 * 4 + r;
                if (EPI == 0) {
                    outp[(size_t)rowg * N + colg] = acc[i][j][r];
                } else {
                    _Float16 h = (_Float16)tanhf(acc[i][j][r] + bv);
                    Ch[(size_t)rowg * N + colg] = h2us(h);
                }
            }
        }
}

// ---- fused: sum 4 split-K parts + bias, softmax over S, zero vocab row, scatter ----
__inline__ __device__ float waveReduceMax(float v) {
    #pragma unroll
    for (int off = 32; off > 0; off >>= 1) v = fmaxf(v, __shfl_down(v, off));
    return v;
}
__inline__ __device__ float waveReduceSum(float v) {
    #pragma unroll
    for (int off = 32; off > 0; off >>= 1) v += __shfl_down(v, off);
    return v;
}

__global__ __launch_bounds__(256) void softmax_scatter(const float* __restrict__ scores,
                                                       const int* __restrict__ tokens,
                                                       const float* __restrict__ ibias,
                                                       float* __restrict__ out) {
    const int row = blockIdx.x;          // b*T + t
    const int b = row >> 8;              // T = 256
    const size_t plane = (size_t)4 * 256 * 512;
    const float* s0 = scores + (size_t)row * 512;
    const float* bi = ibias + (size_t)b * 512;
    const int* tok = tokens + (size_t)b * 512;
    float* o = out + (size_t)row * 32000;

    __shared__ float red[4];
    const int tid = threadIdx.x;
    const int wid = tid >> 6, lane = tid & 63;

    float v0 = bi[tid], v1 = bi[tid + 256];
    #pragma unroll
    for (int p = 0; p < 4; ++p) {
        v0 += s0[p * plane + tid];
        v1 += s0[p * plane + tid + 256];
    }

    float m = fmaxf(v0, v1);
    m = waveReduceMax(m);
    if (lane == 0) red[wid] = m;
    __syncthreads();
    if (tid == 0) red[0] = fmaxf(fmaxf(red[0], red[1]), fmaxf(red[2], red[3]));
    __syncthreads();
    const float rowmax = red[0];
    __syncthreads();

    float e0 = __expf(v0 - rowmax);
    float e1 = __expf(v1 - rowmax);
    float s = e0 + e1;
    s = waveReduceSum(s);
    if (lane == 0) red[wid] = s;
    __syncthreads();
    if (tid == 0) red[0] = red[0] + red[1] + red[2] + red[3];
    __syncthreads();
    const float inv = 1.0f / red[0];

    // zero this row's 32000 vocab slots (row exclusive to this block)
    float4 z = make_float4(0.f, 0.f, 0.f, 0.f);
    float4* o4 = (float4*)o;
    for (int i = tid; i < 8000; i += 256) o4[i] = z;

    __threadfence_block();
    __syncthreads();

    atomicAdd(&o[tok[tid]],       e0 * inv);
    atomicAdd(&o[tok[tid + 256]], e1 * inv);
}

extern "C" void kernel_launch(void* const* d_in, const int* in_sizes, int n_in,
                              void* d_out, int out_size, void* d_ws, size_t ws_size,
                              hipStream_t stream) {
    const int*   inputs  = (const int*)d_in[0];    // [B,S]
    const float* enc_in  = (const float*)d_in[1];  // [2048,1024]
    const float* dec_in  = (const float*)d_in[2];  // [1024,1024]
    const float* ibias   = (const float*)d_in[3];  // [B,S]
    const float* W       = (const float*)d_in[4];  // [1024,1024]
    const float* bproj   = (const float*)d_in[5];  // [1024]
    float* out = (float*)d_out;

    // scores split-K partials (read by scatter while d_out is being zeroed) -> ws: 8 MB
    float* scores = (float*)d_ws;                  // 4 x [4,256,512] fp32

    // all other intermediates live in the dead tail of d_out (zeroed by scatter last)
    size_t outBytes = (size_t)out_size * sizeof(float);
    char* tail = (char*)d_out + outBytes - (size_t)12 * 1024 * 1024;
    unsigned short* Aeh = (unsigned short*)tail;        // enc_in fp16 [2048,1024] 4 MB
    unsigned short* Dh  = Aeh + (size_t)2048 * 1024;    // dec fp16    [1024,1024] 2 MB
    unsigned short* Wth = Dh  + (size_t)1024 * 1024;    // W^T fp16    [1024,1024] 2 MB
    unsigned short* ench = Wth + (size_t)1024 * 1024;   // tanh out    [2048,1024] 4 MB

    // 1) merged prep: converts + W transpose
    prep<<<dim3(3328), 256, 0, stream>>>(enc_in, Aeh, dec_in, Dh, W, Wth);

    // 2) enc = tanh(enc_in @ W + bproj) -> fp16   M=2048,N=1024,K=1024
    gemm_f16<1><<<dim3(16, 32, 1), 256, 0, stream>>>(
        Aeh, Wth, bproj, nullptr, ench,
        1024, 1024, 16, 1, 0LL, 0LL, 0LL, 0LL);

    // 3) scores[b] = dec[b] @ enc[b]^T   per batch M=256,N=512,K=1024, split-K=4
    gemm_f16<0><<<dim3(8, 4, 16), 256, 0, stream>>>(
        Dh, ench, nullptr, scores, nullptr,
        512, 1024, 4, 4,
        (long long)256 * 1024, (long long)512 * 1024,
        (long long)256 * 512, (long long)4 * 256 * 512);

    // 4) sum parts + bias, softmax over S, zero vocab row, scatter-add
    softmax_scatter<<<dim3(4 * 256), 256, 0, stream>>>(scores, inputs, ibias, out);
}